// Round 4
// baseline (138.404 us; speedup 1.0000x reference)
//
#include <hip/hip_runtime.h>
#include <stdint.h>

// Problem dims
#define TDIM 4096
#define HDIM 2048   // N and K of the GEMM

// GEMM tile
#define BM 128
#define BN 128
#define BK 64
#define NKT (HDIM / BK)   // 32
// LDS: per buffer = A region (144 rows = 18 groups of 8 rows, 1KB/group)
//      + B region (128 rows = 16 groups), 128B per row (BK=64 bf16)
#define AREG  18432
#define PERBUF 34816
#define SSTR   132        // S-tile row stride in elements (breaks bank conflicts)

typedef short short8 __attribute__((ext_vector_type(8)));
typedef float f32x4 __attribute__((ext_vector_type(4)));

__device__ __forceinline__ uint16_t f2bf(float f) {
  uint32_t u = __builtin_bit_cast(uint32_t, f);
  u += 0x7fffu + ((u >> 16) & 1u);          // round-to-nearest-even
  return (uint16_t)(u >> 16);
}
__device__ __forceinline__ float bf2f(uint32_t h) {   // low 16 bits used
  uint32_t u = h << 16;
  return __builtin_bit_cast(float, u);
}

__device__ __forceinline__ void async_copy16(const void* gsrc, void* ldst) {
  __builtin_amdgcn_global_load_lds(
      (const __attribute__((address_space(1))) uint32_t*)gsrc,
      (__attribute__((address_space(3))) uint32_t*)ldst,
      16, 0, 0);
}

// ------------- prep: cvt x (fp32->bf16) + transpose/cvt B -> Bt -------------
__global__ void prep(const float* __restrict__ x, const float* __restrict__ B,
                     uint16_t* __restrict__ xb, uint16_t* __restrict__ Bt) {
  __shared__ uint16_t tile[64][70];   // stride 70: even (uint2-aligned), ~2-way banks
  const int t = threadIdx.x;
  if (blockIdx.x < 4096) {
    size_t i = ((size_t)blockIdx.x * 256 + t) * 8;
    float4 v0 = *(const float4*)(x + i);
    float4 v1 = *(const float4*)(x + i + 4);
    union { uint16_t h[8]; uint4 v; } o;
    o.h[0] = f2bf(v0.x); o.h[1] = f2bf(v0.y); o.h[2] = f2bf(v0.z); o.h[3] = f2bf(v0.w);
    o.h[4] = f2bf(v1.x); o.h[5] = f2bf(v1.y); o.h[6] = f2bf(v1.z); o.h[7] = f2bf(v1.w);
    *(uint4*)(xb + i) = o.v;
  } else {
    const int bid = blockIdx.x - 4096;
    const int n0 = (bid & 31) * 64;
    const int k0 = (bid >> 5) * 64;
    {
      const int r  = t >> 4;
      const int c4 = (t & 15) * 4;
#pragma unroll
      for (int i = 0; i < 4; ++i) {
        int rr = r + i * 16;
        float4 v = *(const float4*)&B[(size_t)(k0 + rr) * HDIM + n0 + c4];
        union { uint16_t h[4]; uint2 u; } o;
        o.h[0] = f2bf(v.x); o.h[1] = f2bf(v.y); o.h[2] = f2bf(v.z); o.h[3] = f2bf(v.w);
        *(uint2*)&tile[rr][c4] = o.u;
      }
    }
    __syncthreads();
    {
      // 16B stores: 8 threads per Bt row, 128B contiguous per row
      const int nr8 = t >> 3;           // 0..31
      const int kc8 = (t & 7) * 8;      // 0..56
#pragma unroll
      for (int i = 0; i < 2; ++i) {
        int nr = nr8 + i * 32;
        union { uint16_t h[8]; uint4 v; } o;
#pragma unroll
        for (int j = 0; j < 8; ++j) o.h[j] = tile[kc8 + j][nr];
        *(uint4*)&Bt[(size_t)(n0 + nr) * HDIM + k0 + kc8] = o.v;
      }
    }
  }
}

// --------- fused GEMM + causal exp-decay recurrence (scan) ---------
// S[t][n] = sum_k A[t][k]*Bt[n][k]; out[t][h] = S[t][h] + a[h]*out[t-1][h].
// LATENCY-BOUND finding (R0-R3): at 2 waves/SIMD, per-kt time is ~3550 cyc
// vs ~714 cyc of issue -- traffic/schedule changes were all neutral.
// Fix: 4 waves/SIMD.  512 threads = 8 waves (2M x 4N), wave tile 64x32;
// LDS 69632/block -> 2 blocks/CU -> 16 waves/CU.  VGPR capped at 128 via
// __launch_bounds__(512,4) (4 waves/SIMD needs <=128).
// Two-phase K-tile schedule (counted vmcnt, setprio on MFMA) from R3.
// BK=64: 128B rows + XOR-8 chunk swizzle = conflict-free.
// 16 warmup rows on waves 0-3 (one 32-col slice each); in-LDS S-tile scan
// epilogue (|a| <= 2^-5 -> a^16 below fp32 noise, chunks independent).
__global__ __launch_bounds__(512, 4) void gemm_scan(
    const uint16_t* __restrict__ A, const uint16_t* __restrict__ Bt,
    const float* __restrict__ a, float* __restrict__ out) {
  __shared__ __align__(16) char lds[2 * PERBUF];   // 69632

  const int tid  = threadIdx.x;
  const int lane = tid & 63;
  const int wave = tid >> 6;            // 0..7
  const int wm = (wave >> 2) * 64;      // wave row offset {0,64}
  const int wn = (wave & 3) * 32;       // wave col offset {0,32,64,96}

  // XCD-chunked bijective swizzle: 512 blocks, 8 XCDs, 64 consecutive
  // logical tiles per XCD -> the 16 blocks sharing an A-panel colocate.
  const int flat = blockIdx.y * gridDim.x + blockIdx.x;
  const int logi = (flat & 7) * 64 + (flat >> 3);
  const int m0 = (logi >> 4) * BM;      // 32 m-blocks
  const int n0 = (logi & 15) * BN;      // 16 n-blocks

  f32x4 acc[4][2] = {};
  f32x4 accw[2] = {};                   // warmup rows (waves 0-3, own cols)

  // staging: one instr = 8 rows x 128B (1KB); lane l: row lr=l>>3, slot l&7,
  // fetches global chunk (l&7)^lr -> LDS slot c of row r holds chunk c^(r&7)
  const int lr = lane >> 3;             // 0..7
  const int gc = (lane & 7) ^ lr;       // swizzled 16B chunk to fetch

  const int fr = lane & 15;
  const int fq = lane >> 4;             // 0..3

  // A: 18 groups of 8 rows (t in [m0-16, m0+128)); wave w takes {w, w+8},
  // waves 0,1 also {16+w} (phase 0).  B: 16 groups; wave w takes {2w,2w+1}
  // (phase 1).  Counted vmcnt: 3 (w0,w1) / 2 in flight.
  auto issue_A = [&](int kt2) {
    size_t koff = (size_t)kt2 * (BK * 2);
    char* dst = lds + (kt2 & 1) * PERBUF;
    {
      int g = wave;
      int row = m0 - 16 + g * 8 + lr;
      if (row < 0) row = 0;             // m0==0: garbage rows, never used
      async_copy16((const char*)A + ((size_t)row * HDIM + gc * 8) * 2 + koff,
                   dst + g * 1024);
    }
    {
      int g = wave + 8;                 // rows >= m0+48: always valid
      int row = m0 - 16 + g * 8 + lr;
      async_copy16((const char*)A + ((size_t)row * HDIM + gc * 8) * 2 + koff,
                   dst + g * 1024);
    }
    if (wave < 2) {
      int g = 16 + wave;                // rows m0+112..m0+127: always valid
      int row = m0 - 16 + g * 8 + lr;
      async_copy16((const char*)A + ((size_t)row * HDIM + gc * 8) * 2 + koff,
                   dst + g * 1024);
    }
  };
  auto issue_B = [&](int kt2) {
    size_t koff = (size_t)kt2 * (BK * 2);
    char* dst = lds + (kt2 & 1) * PERBUF;
#pragma unroll
    for (int i = 0; i < 2; ++i) {
      int g = wave * 2 + i;
      int row = n0 + g * 8 + lr;
      async_copy16((const char*)Bt + ((size_t)row * HDIM + gc * 8) * 2 + koff,
                   dst + AREG + g * 1024);
    }
  };

  issue_A(0);
  issue_B(0);

  for (int kt = 0; kt < NKT; ++kt) {
    const char* base = lds + (kt & 1) * PERBUF;

    // ---------- phase 0: K-half s=0 ----------
    if (kt + 1 < NKT) {
      issue_A(kt + 1);
      // wait this tile's loads; the 2-3 just-issued stay in flight
      if (wave < 2) asm volatile("s_waitcnt vmcnt(3)" ::: "memory");
      else          asm volatile("s_waitcnt vmcnt(2)" ::: "memory");
    } else {
      asm volatile("s_waitcnt vmcnt(0)" ::: "memory");
    }
    asm volatile("s_barrier" ::: "memory");
    {
      short8 af[4], bfr[2];
#pragma unroll
      for (int im = 0; im < 4; ++im)
        af[im] = *(const short8*)(base + (16 + wm + im * 16 + fr) * 128 +
                                  ((fq ^ (fr & 7)) * 16));
#pragma unroll
      for (int in = 0; in < 2; ++in)
        bfr[in] = *(const short8*)(base + AREG + (wn + in * 16 + fr) * 128 +
                                   ((fq ^ (fr & 7)) * 16));
      short8 aw = af[0];
      if (wave < 4)
        aw = *(const short8*)(base + fr * 128 + ((fq ^ (fr & 7)) * 16));
      asm volatile("s_waitcnt lgkmcnt(0)" ::: "memory");
      __builtin_amdgcn_sched_barrier(0);
      __builtin_amdgcn_s_setprio(1);
#pragma unroll
      for (int im = 0; im < 4; ++im)
#pragma unroll
        for (int in = 0; in < 2; ++in)
          acc[im][in] = __builtin_amdgcn_mfma_f32_16x16x32_bf16(
              af[im], bfr[in], acc[im][in], 0, 0, 0);
      if (wave < 4) {
#pragma unroll
        for (int in = 0; in < 2; ++in)
          accw[in] = __builtin_amdgcn_mfma_f32_16x16x32_bf16(
              aw, bfr[in], accw[in], 0, 0, 0);
      }
      __builtin_amdgcn_s_setprio(0);
    }

    // ---------- phase 1: K-half s=1 ----------
    {
      short8 af[4], bfr[2];
#pragma unroll
      for (int im = 0; im < 4; ++im)
        af[im] = *(const short8*)(base + (16 + wm + im * 16 + fr) * 128 +
                                  (((4 + fq) ^ (fr & 7)) * 16));
#pragma unroll
      for (int in = 0; in < 2; ++in)
        bfr[in] = *(const short8*)(base + AREG + (wn + in * 16 + fr) * 128 +
                                   (((4 + fq) ^ (fr & 7)) * 16));
      short8 aw = af[0];
      if (wave < 4)
        aw = *(const short8*)(base + fr * 128 + (((4 + fq) ^ (fr & 7)) * 16));
      if (kt + 1 < NKT) issue_B(kt + 1);
      // barrier AFTER the reads: this buffer is only re-staged (issue_A at
      // kt+1 phase 0) once every wave's reads are enqueued.
      asm volatile("s_barrier" ::: "memory");
      asm volatile("s_waitcnt lgkmcnt(0)" ::: "memory");
      __builtin_amdgcn_sched_barrier(0);
      __builtin_amdgcn_s_setprio(1);
#pragma unroll
      for (int im = 0; im < 4; ++im)
#pragma unroll
        for (int in = 0; in < 2; ++in)
          acc[im][in] = __builtin_amdgcn_mfma_f32_16x16x32_bf16(
              af[im], bfr[in], acc[im][in], 0, 0, 0);
      if (wave < 4) {
#pragma unroll
        for (int in = 0; in < 2; ++in)
          accw[in] = __builtin_amdgcn_mfma_f32_16x16x32_bf16(
              aw, bfr[in], accw[in], 0, 0, 0);
      }
      __builtin_amdgcn_s_setprio(0);
    }
  }

  __syncthreads();   // all reads of both buffers done before S-tile overwrite

  // ---- epilogue: S-tile (144 x 128, bf16, stride 132) into LDS ----
  uint16_t* Sl = (uint16_t*)lds;
#pragma unroll
  for (int im = 0; im < 4; ++im)
#pragma unroll
    for (int in = 0; in < 2; ++in)
#pragma unroll
      for (int r = 0; r < 4; ++r)
        Sl[(16 + wm + im * 16 + fq * 4 + r) * SSTR + wn + in * 16 + fr] =
            f2bf(acc[im][in][r]);
  if (wave < 4) {
#pragma unroll
    for (int in = 0; in < 2; ++in)
#pragma unroll
      for (int r = 0; r < 4; ++r)
        Sl[(fq * 4 + r) * SSTR + wn + in * 16 + fr] = f2bf(accw[in][r]);
  }
  __syncthreads();

  // ---- scan: 4 threads per column, 32 t-steps each, 16-step warmup ----
  const int col   = tid & 127;
  const int chunk = tid >> 7;           // 0..3
  const float av  = a[n0 + col];
  float h = 0.f;
  if (!(m0 == 0 && chunk == 0)) {
#pragma unroll
    for (int i = 0; i < 16; ++i)
      h = av * h + bf2f(Sl[(chunk * 32 + i) * SSTR + col]);
  }
  float* op = out + (size_t)(m0 + chunk * 32) * HDIM + n0 + col;
#pragma unroll
  for (int i = 0; i < 32; ++i) {
    h = av * h + bf2f(Sl[(chunk * 32 + 16 + i) * SSTR + col]);
    op[(size_t)i * HDIM] = h;
  }
}

extern "C" void kernel_launch(void* const* d_in, const int* in_sizes, int n_in,
                              void* d_out, int out_size, void* d_ws, size_t ws_size,
                              hipStream_t stream) {
  const float* x = (const float*)d_in[0];   // (T, H)
  const float* a = (const float*)d_in[1];   // (H,)
  const float* B = (const float*)d_in[2];   // (H, H)
  float* out = (float*)d_out;               // (1, T, H) fp32

  uint16_t* xb  = (uint16_t*)d_ws;                                        // 16 MB
  uint16_t* Btb = (uint16_t*)((char*)d_ws + (size_t)16 * 1024 * 1024);    //  8 MB

  // x -> bf16  and  B -> Bt bf16 (fused)
  prep<<<4096 + 1024, 256, 0, stream>>>(x, B, xb, Btb);
  // fused GEMM + recurrence: 512 blocks x 512 threads (8 waves, 64x32 each)
  gemm_scan<<<dim3(HDIM / BN, TDIM / BM), 512, 0, stream>>>(xb, Btb, a, out);
}